// Round 1
// baseline (1728.575 us; speedup 1.0000x reference)
//
#include <hip/hip_runtime.h>
#include <math.h>

// ---------------- degree / norm ----------------

__global__ void k_deg(const int* __restrict__ ei, int E, float* __restrict__ deg) {
    int e = blockIdx.x * 256 + threadIdx.x;
    if (e < E) atomicAdd(deg + ei[E + e], 1.0f);   // dst row of edge_index
}

__global__ void k_dinv(float* __restrict__ d, int n) {
    int i = blockIdx.x * 256 + threadIdx.x;
    if (i < n) d[i] = rsqrtf(d[i] + 1.0f);         // +1 = self loop; deg>=1 always
}

// ---------------- self-loop init + edge scatter ----------------
// selfloop fully initializes the accumulator (no memset needed): acc[i] = feat[i]*dinv[i]^2

template<int LOGD4>
__global__ void k_selfloop(const float* __restrict__ feat, const float* __restrict__ dinv,
                           float* __restrict__ out, int total4) {
    int idx = blockIdx.x * 256 + threadIdx.x;
    if (idx >= total4) return;
    int i = idx >> LOGD4;
    float s = dinv[i]; s *= s;
    float4 v = ((const float4*)feat)[idx];
    v.x *= s; v.y *= s; v.z *= s; v.w *= s;
    ((float4*)out)[idx] = v;
}

template<int LOGD4>
__global__ void k_edge_agg(const int* __restrict__ ei, int E,
                           const float* __restrict__ dinv,
                           const float* __restrict__ feat,
                           float* __restrict__ acc) {
    int idx = blockIdx.x * 256 + threadIdx.x;
    int total = E << LOGD4;
    if (idx >= total) return;
    int e  = idx >> LOGD4;
    int c4 = idx & ((1 << LOGD4) - 1);
    int s = ei[e], t = ei[E + e];
    float nrm = dinv[s] * dinv[t];
    const int D = 4 << LOGD4;
    float4 v = ((const float4*)(feat + (size_t)s * D))[c4];
    float* o = acc + (size_t)t * D + (c4 << 2);
    atomicAdd(o + 0, v.x * nrm);
    atomicAdd(o + 1, v.y * nrm);
    atomicAdd(o + 2, v.z * nrm);
    atomicAdd(o + 3, v.w * nrm);
}

// ---------------- GEMM1: C[M,256] = relu(A[M,128] @ W[128,256] + b) ----------------
// 64x64 tile, 256 threads, 4x4 micro-kernel. As[m][k] pad->132 so the 4 scalar
// A reads per k are bank-broadcast and the float4 tile-store stays 16B aligned.

__global__ __launch_bounds__(256) void k_gemm1(
    const float* __restrict__ A, const float* __restrict__ W,
    const float* __restrict__ bias, float* __restrict__ C, int M)
{
    __shared__ float As[64][132];
    __shared__ float Bs[128][64];
    const int t  = threadIdx.x;
    const int mb = blockIdx.x * 64;
    const int nb = blockIdx.y * 64;

    #pragma unroll
    for (int it = 0; it < 8; ++it) {              // A tile: 64 x 128
        int idx = it * 256 + t;
        int r = idx >> 5, c4 = idx & 31;
        float4 v = make_float4(0.f, 0.f, 0.f, 0.f);
        int gr = mb + r;
        if (gr < M) v = *(const float4*)(A + (size_t)gr * 128 + (c4 << 2));
        *(float4*)&As[r][c4 << 2] = v;
    }
    #pragma unroll
    for (int it = 0; it < 8; ++it) {              // B tile: 128 x 64
        int idx = it * 256 + t;
        int r = idx >> 4, c4 = idx & 15;
        *(float4*)&Bs[r][c4 << 2] = *(const float4*)(W + (size_t)r * 256 + nb + (c4 << 2));
    }
    __syncthreads();

    const int tx = t & 15, ty = t >> 4;
    float acc[4][4] = {};
    #pragma unroll 8
    for (int k = 0; k < 128; ++k) {
        float a0 = As[ty * 4 + 0][k];
        float a1 = As[ty * 4 + 1][k];
        float a2 = As[ty * 4 + 2][k];
        float a3 = As[ty * 4 + 3][k];
        float4 b = *(const float4*)&Bs[k][tx << 2];
        acc[0][0] += a0 * b.x; acc[0][1] += a0 * b.y; acc[0][2] += a0 * b.z; acc[0][3] += a0 * b.w;
        acc[1][0] += a1 * b.x; acc[1][1] += a1 * b.y; acc[1][2] += a1 * b.z; acc[1][3] += a1 * b.w;
        acc[2][0] += a2 * b.x; acc[2][1] += a2 * b.y; acc[2][2] += a2 * b.z; acc[2][3] += a2 * b.w;
        acc[3][0] += a3 * b.x; acc[3][1] += a3 * b.y; acc[3][2] += a3 * b.z; acc[3][3] += a3 * b.w;
    }

    float4 bv = *(const float4*)(bias + nb + (tx << 2));
    #pragma unroll
    for (int i = 0; i < 4; ++i) {
        int gr = mb + ty * 4 + i;
        if (gr < M) {
            float4 o;
            o.x = fmaxf(acc[i][0] + bv.x, 0.f);
            o.y = fmaxf(acc[i][1] + bv.y, 0.f);
            o.z = fmaxf(acc[i][2] + bv.z, 0.f);
            o.w = fmaxf(acc[i][3] + bv.w, 0.f);
            *(float4*)(C + (size_t)gr * 256 + nb + (tx << 2)) = o;
        }
    }
}

// ---------------- GEMM2: O[M,16] = H[M,256] @ W2[256,16] ----------------
// 128 threads, 32 rows/block; thread = (row, 4-col group); Hs pad->260 keeps
// float4 reads 16B-aligned and 2-way (free) on banks.

__global__ __launch_bounds__(128) void k_gemm2(
    const float* __restrict__ H, const float* __restrict__ Wt,
    float* __restrict__ O, int M)
{
    __shared__ float Hs[32][260];
    __shared__ float Ws[256][16];
    const int t  = threadIdx.x;
    const int mb = blockIdx.x * 32;

    #pragma unroll
    for (int it = 0; it < 8; ++it) {              // W2: 256x16
        int idx = it * 128 + t;
        int k = idx >> 2, c4 = idx & 3;
        *(float4*)&Ws[k][c4 << 2] = *(const float4*)(Wt + k * 16 + (c4 << 2));
    }
    #pragma unroll
    for (int it = 0; it < 16; ++it) {             // H tile: 32x256
        int idx = it * 128 + t;
        int r = idx >> 6, c4 = idx & 63;
        float4 v = make_float4(0.f, 0.f, 0.f, 0.f);
        int gr = mb + r;
        if (gr < M) v = *(const float4*)(H + (size_t)gr * 256 + (c4 << 2));
        *(float4*)&Hs[r][c4 << 2] = v;
    }
    __syncthreads();

    const int row = t >> 2, cg = t & 3;
    float a0 = 0.f, a1 = 0.f, a2 = 0.f, a3 = 0.f;
    #pragma unroll 8
    for (int k4 = 0; k4 < 64; ++k4) {
        float4 a  = *(const float4*)&Hs[row][k4 << 2];
        float4 b0 = *(const float4*)&Ws[k4 * 4 + 0][cg << 2];
        float4 b1 = *(const float4*)&Ws[k4 * 4 + 1][cg << 2];
        float4 b2 = *(const float4*)&Ws[k4 * 4 + 2][cg << 2];
        float4 b3 = *(const float4*)&Ws[k4 * 4 + 3][cg << 2];
        a0 += a.x * b0.x + a.y * b1.x + a.z * b2.x + a.w * b3.x;
        a1 += a.x * b0.y + a.y * b1.y + a.z * b2.y + a.w * b3.y;
        a2 += a.x * b0.z + a.y * b1.z + a.z * b2.z + a.w * b3.z;
        a3 += a.x * b0.w + a.y * b1.w + a.z * b2.w + a.w * b3.w;
    }
    int gr = mb + row;
    if (gr < M) *(float4*)(O + (size_t)gr * 16 + (cg << 2)) = make_float4(a0, a1, a2, a3);
}

// ---------------- log_softmax over 16 classes (+ b2) ----------------

__global__ void k_logsm(float* __restrict__ out, const float* __restrict__ b2, int n) {
    int i = blockIdx.x * 256 + threadIdx.x;
    if (i >= n) return;
    float4* p = (float4*)(out + (size_t)i * 16);
    float v[16];
    #pragma unroll
    for (int j = 0; j < 4; ++j) {
        float4 w  = p[j];
        float4 bb = ((const float4*)b2)[j];
        v[j * 4 + 0] = w.x + bb.x; v[j * 4 + 1] = w.y + bb.y;
        v[j * 4 + 2] = w.z + bb.z; v[j * 4 + 3] = w.w + bb.w;
    }
    float m = v[0];
    #pragma unroll
    for (int j = 1; j < 16; ++j) m = fmaxf(m, v[j]);
    float s = 0.f;
    #pragma unroll
    for (int j = 0; j < 16; ++j) s += __expf(v[j] - m);
    float lse = m + __logf(s);
    #pragma unroll
    for (int j = 0; j < 4; ++j) {
        float4 w;
        w.x = v[j * 4 + 0] - lse; w.y = v[j * 4 + 1] - lse;
        w.z = v[j * 4 + 2] - lse; w.w = v[j * 4 + 3] - lse;
        p[j] = w;
    }
}

// ---------------- launcher ----------------

extern "C" void kernel_launch(void* const* d_in, const int* in_sizes, int n_in,
                              void* d_out, int out_size, void* d_ws, size_t ws_size,
                              hipStream_t stream) {
    const float* x  = (const float*)d_in[0];   // [N,128]
    const int*   ei = (const int*)d_in[1];     // [2,E] int32
    const float* W1 = (const float*)d_in[2];   // [128,256]
    const float* b1 = (const float*)d_in[3];   // [256]
    const float* W2 = (const float*)d_in[4];   // [256,16]
    const float* b2 = (const float*)d_in[5];   // [16]
    float* out = (float*)d_out;                // [N,16]

    const int N = in_sizes[0] / 128;           // 50000
    const int E = in_sizes[1] / 2;             // 800000

    // workspace layout (floats), 256-aligned offsets
    float* ws   = (float*)d_ws;
    float* dinv = ws;                          // N (deg -> dinv in place)
    float* agg1 = ws + 51200;                  // N*128
    float* h    = agg1 + (size_t)N * 128;      // N*256
    float* h2   = h + (size_t)N * 256;         // N*16
    // total ~80.3 MB

    // degree (d_ws is poisoned 0xAA every call -> must re-zero)
    hipMemsetAsync(dinv, 0, (size_t)N * sizeof(float), stream);
    k_deg <<<(E + 255) / 256, 256, 0, stream>>>(ei, E, dinv);
    k_dinv<<<(N + 255) / 256, 256, 0, stream>>>(dinv, N);

    // layer 1: aggregate x (D=128) then GEMM+bias+relu
    {
        int total4 = N * 32;
        k_selfloop<5><<<(total4 + 255) / 256, 256, 0, stream>>>(x, dinv, agg1, total4);
        int total = E * 32;
        k_edge_agg<5><<<(total + 255) / 256, 256, 0, stream>>>(ei, E, dinv, x, agg1);
        dim3 g((N + 63) / 64, 4);
        k_gemm1<<<g, 256, 0, stream>>>(agg1, W1, b1, h, N);
    }

    // layer 2: GEMM (D=16) then aggregate, then log_softmax(+b2)
    {
        k_gemm2<<<(N + 31) / 32, 128, 0, stream>>>(h, W2, h2, N);
        int total4 = N * 4;
        k_selfloop<2><<<(total4 + 255) / 256, 256, 0, stream>>>(h2, dinv, out, total4);
        int total = E * 4;
        k_edge_agg<2><<<(total + 255) / 256, 256, 0, stream>>>(ei, E, dinv, h2, out);
        k_logsm<<<(N + 255) / 256, 256, 0, stream>>>(out, b2, N);
    }
}

// Round 2
// 357.123 us; speedup vs baseline: 4.8403x; 4.8403x over previous
//
#include <hip/hip_runtime.h>
#include <math.h>

// =========================================================================
// CSR build: counts -> exclusive scan -> scatter. No feature atomics.
// =========================================================================

__global__ void k_deg_count(const int* __restrict__ ei, int E, int* __restrict__ cnt) {
    int e = blockIdx.x * 256 + threadIdx.x;
    if (e < E) atomicAdd(cnt + ei[E + e], 1);      // dst row
}

__global__ void k_dinv(const int* __restrict__ cnt, float* __restrict__ dinv, int n) {
    int i = blockIdx.x * 256 + threadIdx.x;
    if (i < n) dinv[i] = rsqrtf((float)cnt[i] + 1.0f);  // +1 self loop
}

// 3-kernel exclusive scan over n<=65536 (needs nb<=256)
__global__ void k_scan_block(const int* __restrict__ cnt, int n,
                             int* __restrict__ pos, int* __restrict__ bsum) {
    __shared__ int tmp[256];
    int i = blockIdx.x * 256 + threadIdx.x;
    int v = (i < n) ? cnt[i] : 0;
    tmp[threadIdx.x] = v; __syncthreads();
    #pragma unroll
    for (int off = 1; off < 256; off <<= 1) {
        int t = (threadIdx.x >= off) ? tmp[threadIdx.x - off] : 0;
        __syncthreads();
        tmp[threadIdx.x] += t;
        __syncthreads();
    }
    if (i < n) pos[i] = tmp[threadIdx.x] - v;      // exclusive
    if (threadIdx.x == 255) bsum[blockIdx.x] = tmp[255];
}

__global__ void k_scan_bsum(int* __restrict__ bsum, int nb) {
    __shared__ int tmp[256];
    int v = (threadIdx.x < nb) ? bsum[threadIdx.x] : 0;
    tmp[threadIdx.x] = v; __syncthreads();
    #pragma unroll
    for (int off = 1; off < 256; off <<= 1) {
        int t = (threadIdx.x >= off) ? tmp[threadIdx.x - off] : 0;
        __syncthreads();
        tmp[threadIdx.x] += t;
        __syncthreads();
    }
    if (threadIdx.x < nb) bsum[threadIdx.x] = tmp[threadIdx.x] - v;
}

__global__ void k_scan_add(int* __restrict__ pos, int n, const int* __restrict__ bsum) {
    int i = blockIdx.x * 256 + threadIdx.x;
    if (i < n) pos[i] += bsum[blockIdx.x];
}

__global__ void k_scatter(const int* __restrict__ ei, int E,
                          const int* __restrict__ rs, int* __restrict__ cursor,
                          int* __restrict__ col) {
    int e = blockIdx.x * 256 + threadIdx.x;
    if (e >= E) return;
    int s = ei[e], t = ei[E + e];
    int p = rs[t] + atomicAdd(cursor + t, 1);
    col[p] = s;
}

// =========================================================================
// CSR aggregation. Layer 1 (D=128): one wave per dst node, lane owns float2.
// Gather 512 B/edge coalesced, one clean 512 B store per node.
// =========================================================================

__global__ __launch_bounds__(256) void k_agg_csr128(
    const int* __restrict__ rs, const int* __restrict__ col,
    const float* __restrict__ dinv, const float* __restrict__ x,
    float* __restrict__ out, int n, int E)
{
    int node = (blockIdx.x * 256 + threadIdx.x) >> 6;
    int lane = threadIdx.x & 63;
    if (node >= n) return;
    float di = dinv[node];
    int beg = rs[node];
    int end = (node + 1 < n) ? rs[node + 1] : E;
    const float2* xr = (const float2*)x;
    float2 v = xr[(size_t)node * 64 + lane];       // self loop
    float s = di * di;
    float ax = v.x * s, ay = v.y * s;
    for (int j = beg; j < end; ++j) {
        int src = col[j];
        float nrm = dinv[src] * di;
        float2 u = xr[(size_t)src * 64 + lane];
        ax += u.x * nrm; ay += u.y * nrm;
    }
    ((float2*)out)[(size_t)node * 64 + lane] = make_float2(ax, ay);
}

// Layer 2 (D=16): 16 lanes per node (4 nodes/wave), fused +b2 + log_softmax
__global__ __launch_bounds__(256) void k_agg_csr16_lsm(
    const int* __restrict__ rs, const int* __restrict__ col,
    const float* __restrict__ dinv, const float* __restrict__ h2,
    const float* __restrict__ b2, float* __restrict__ out, int n, int E)
{
    int node = (blockIdx.x * 256 + threadIdx.x) >> 4;
    int lane = threadIdx.x & 15;
    if (node >= n) return;
    float di = dinv[node];
    int beg = rs[node];
    int end = (node + 1 < n) ? rs[node + 1] : E;
    float acc = h2[(size_t)node * 16 + lane] * di * di;   // self loop
    for (int j = beg; j < end; ++j) {
        int src = col[j];
        acc += h2[(size_t)src * 16 + lane] * (dinv[src] * di);
    }
    acc += b2[lane];
    // log_softmax over the 16 lanes of this quarter-wave
    float m = acc;
    #pragma unroll
    for (int msk = 1; msk < 16; msk <<= 1) m = fmaxf(m, __shfl_xor(m, msk, 16));
    float ex = __expf(acc - m);
    float ssum = ex;
    #pragma unroll
    for (int msk = 1; msk < 16; msk <<= 1) ssum += __shfl_xor(ssum, msk, 16);
    out[(size_t)node * 16 + lane] = acc - m - __logf(ssum);
}

// =========================================================================
// GEMM1: C[M,256] = relu(A[M,128] @ W[128,256] + b)
// =========================================================================

__global__ __launch_bounds__(256) void k_gemm1(
    const float* __restrict__ A, const float* __restrict__ W,
    const float* __restrict__ bias, float* __restrict__ C, int M)
{
    __shared__ float As[64][132];
    __shared__ float Bs[128][64];
    const int t  = threadIdx.x;
    const int mb = blockIdx.x * 64;
    const int nb = blockIdx.y * 64;

    #pragma unroll
    for (int it = 0; it < 8; ++it) {              // A tile: 64 x 128
        int idx = it * 256 + t;
        int r = idx >> 5, c4 = idx & 31;
        float4 v = make_float4(0.f, 0.f, 0.f, 0.f);
        int gr = mb + r;
        if (gr < M) v = *(const float4*)(A + (size_t)gr * 128 + (c4 << 2));
        *(float4*)&As[r][c4 << 2] = v;
    }
    #pragma unroll
    for (int it = 0; it < 8; ++it) {              // B tile: 128 x 64
        int idx = it * 256 + t;
        int r = idx >> 4, c4 = idx & 15;
        *(float4*)&Bs[r][c4 << 2] = *(const float4*)(W + (size_t)r * 256 + nb + (c4 << 2));
    }
    __syncthreads();

    const int tx = t & 15, ty = t >> 4;
    float acc[4][4] = {};
    #pragma unroll 8
    for (int k = 0; k < 128; ++k) {
        float a0 = As[ty * 4 + 0][k];
        float a1 = As[ty * 4 + 1][k];
        float a2 = As[ty * 4 + 2][k];
        float a3 = As[ty * 4 + 3][k];
        float4 b = *(const float4*)&Bs[k][tx << 2];
        acc[0][0] += a0 * b.x; acc[0][1] += a0 * b.y; acc[0][2] += a0 * b.z; acc[0][3] += a0 * b.w;
        acc[1][0] += a1 * b.x; acc[1][1] += a1 * b.y; acc[1][2] += a1 * b.z; acc[1][3] += a1 * b.w;
        acc[2][0] += a2 * b.x; acc[2][1] += a2 * b.y; acc[2][2] += a2 * b.z; acc[2][3] += a2 * b.w;
        acc[3][0] += a3 * b.x; acc[3][1] += a3 * b.y; acc[3][2] += a3 * b.z; acc[3][3] += a3 * b.w;
    }

    float4 bv = *(const float4*)(bias + nb + (tx << 2));
    #pragma unroll
    for (int i = 0; i < 4; ++i) {
        int gr = mb + ty * 4 + i;
        if (gr < M) {
            float4 o;
            o.x = fmaxf(acc[i][0] + bv.x, 0.f);
            o.y = fmaxf(acc[i][1] + bv.y, 0.f);
            o.z = fmaxf(acc[i][2] + bv.z, 0.f);
            o.w = fmaxf(acc[i][3] + bv.w, 0.f);
            *(float4*)(C + (size_t)gr * 256 + nb + (tx << 2)) = o;
        }
    }
}

// =========================================================================
// GEMM2: O[M,16] = H[M,256] @ W2[256,16]
// =========================================================================

__global__ __launch_bounds__(128) void k_gemm2(
    const float* __restrict__ H, const float* __restrict__ Wt,
    float* __restrict__ O, int M)
{
    __shared__ float Hs[32][260];
    __shared__ float Ws[256][16];
    const int t  = threadIdx.x;
    const int mb = blockIdx.x * 32;

    #pragma unroll
    for (int it = 0; it < 8; ++it) {              // W2: 256x16
        int idx = it * 128 + t;
        int k = idx >> 2, c4 = idx & 3;
        *(float4*)&Ws[k][c4 << 2] = *(const float4*)(Wt + k * 16 + (c4 << 2));
    }
    #pragma unroll
    for (int it = 0; it < 16; ++it) {             // H tile: 32x256
        int idx = it * 128 + t;
        int r = idx >> 6, c4 = idx & 63;
        float4 v = make_float4(0.f, 0.f, 0.f, 0.f);
        int gr = mb + r;
        if (gr < M) v = *(const float4*)(H + (size_t)gr * 256 + (c4 << 2));
        *(float4*)&Hs[r][c4 << 2] = v;
    }
    __syncthreads();

    const int row = t >> 2, cg = t & 3;
    float a0 = 0.f, a1 = 0.f, a2 = 0.f, a3 = 0.f;
    #pragma unroll 8
    for (int k4 = 0; k4 < 64; ++k4) {
        float4 a  = *(const float4*)&Hs[row][k4 << 2];
        float4 b0 = *(const float4*)&Ws[k4 * 4 + 0][cg << 2];
        float4 b1 = *(const float4*)&Ws[k4 * 4 + 1][cg << 2];
        float4 b2 = *(const float4*)&Ws[k4 * 4 + 2][cg << 2];
        float4 b3 = *(const float4*)&Ws[k4 * 4 + 3][cg << 2];
        a0 += a.x * b0.x + a.y * b1.x + a.z * b2.x + a.w * b3.x;
        a1 += a.x * b0.y + a.y * b1.y + a.z * b2.y + a.w * b3.y;
        a2 += a.x * b0.z + a.y * b1.z + a.z * b2.z + a.w * b3.z;
        a3 += a.x * b0.w + a.y * b1.w + a.z * b2.w + a.w * b3.w;
    }
    int gr = mb + row;
    if (gr < M) *(float4*)(O + (size_t)gr * 16 + (cg << 2)) = make_float4(a0, a1, a2, a3);
}

// =========================================================================
// launcher
// =========================================================================

extern "C" void kernel_launch(void* const* d_in, const int* in_sizes, int n_in,
                              void* d_out, int out_size, void* d_ws, size_t ws_size,
                              hipStream_t stream) {
    const float* x  = (const float*)d_in[0];   // [N,128]
    const int*   ei = (const int*)d_in[1];     // [2,E]
    const float* W1 = (const float*)d_in[2];   // [128,256]
    const float* b1 = (const float*)d_in[3];   // [256]
    const float* W2 = (const float*)d_in[4];   // [256,16]
    const float* b2 = (const float*)d_in[5];   // [16]
    float* out = (float*)d_out;                // [N,16]

    const int N = in_sizes[0] / 128;           // 50000
    const int E = in_sizes[1] / 2;             // 800000

    // workspace layout in 4-byte words from base
    float* ws    = (float*)d_ws;
    float* dinv  = ws;                             // [0, 51200)
    int*   cnt   = (int*)(ws + 51200);             // [51200, 102400)  also cursor
    int*   rs    = (int*)(ws + 102400);            // [102400, 153600)
    int*   bsum  = (int*)(ws + 153600);            // [153600, 154624)
    int*   col   = (int*)(ws + 154624);            // [154624, 954624)
    float* agg1  = ws + 954624;                    // N*128 = 6.4M words
    float* h     = agg1 + (size_t)N * 128;         // N*256 = 12.8M words
    float* h2    = agg1;                           // aliases agg1 (dead after gemm1)
    // total ~80.6 MB

    const int NB = (N + 255) / 256;                // 196 scan blocks

    // ---- CSR build ----
    hipMemsetAsync(cnt, 0, (size_t)N * sizeof(int), stream);
    k_deg_count<<<(E + 255) / 256, 256, 0, stream>>>(ei, E, cnt);
    k_dinv     <<<NB, 256, 0, stream>>>(cnt, dinv, N);
    k_scan_block<<<NB, 256, 0, stream>>>(cnt, N, rs, bsum);
    k_scan_bsum <<<1, 256, 0, stream>>>(bsum, NB);
    k_scan_add  <<<NB, 256, 0, stream>>>(rs, N, bsum);
    hipMemsetAsync(cnt, 0, (size_t)N * sizeof(int), stream);   // -> cursor
    k_scatter  <<<(E + 255) / 256, 256, 0, stream>>>(ei, E, rs, cnt, col);

    // ---- layer 1: aggregate x (D=128), then GEMM+bias+relu ----
    {
        int thr = N * 64;   // one wave per node
        k_agg_csr128<<<(thr + 255) / 256, 256, 0, stream>>>(rs, col, dinv, x, agg1, N, E);
        dim3 g((N + 63) / 64, 4);
        k_gemm1<<<g, 256, 0, stream>>>(agg1, W1, b1, h, N);
    }

    // ---- layer 2: GEMM (D=16), then aggregate + b2 + log_softmax ----
    {
        k_gemm2<<<(N + 31) / 32, 128, 0, stream>>>(h, W2, h2, N);
        int thr = N * 16;   // 16 lanes per node
        k_agg_csr16_lsm<<<(thr + 255) / 256, 256, 0, stream>>>(rs, col, dinv, h2, b2, out, N, E);
    }
}

// Round 3
// 304.648 us; speedup vs baseline: 5.6740x; 1.1722x over previous
//
#include <hip/hip_runtime.h>
#include <math.h>

typedef unsigned int uint;

// ---------------- bf16 helpers (OCP bf16 = top 16 bits of fp32, RNE) ----------

__device__ __forceinline__ float blo(uint u) { return __uint_as_float(u << 16); }
__device__ __forceinline__ float bhi(uint u) { return __uint_as_float(u & 0xffff0000u); }
__device__ __forceinline__ uint pack_bf16(float a, float b) {
    uint ua = __float_as_uint(a), ub = __float_as_uint(b);
    ua = (ua + 0x7fffu + ((ua >> 16) & 1u)) >> 16;
    ub = (ub + 0x7fffu + ((ub >> 16) & 1u)) >> 16;
    return ua | (ub << 16);
}

// =========================================================================
// CSR build
// =========================================================================

__global__ void k_deg_count(const int* __restrict__ ei, int E, int* __restrict__ cnt) {
    int e = blockIdx.x * 256 + threadIdx.x;
    if (e < E) atomicAdd(cnt + ei[E + e], 1);      // dst row
}

// exclusive scan over n<=65536 (nb<=256), dinv fused in
__global__ void k_scan_block(const int* __restrict__ cnt, int n,
                             int* __restrict__ pos, int* __restrict__ bsum,
                             float* __restrict__ dinv) {
    __shared__ int tmp[256];
    int i = blockIdx.x * 256 + threadIdx.x;
    int v = (i < n) ? cnt[i] : 0;
    if (i < n) dinv[i] = rsqrtf((float)v + 1.0f);   // +1 self loop
    tmp[threadIdx.x] = v; __syncthreads();
    #pragma unroll
    for (int off = 1; off < 256; off <<= 1) {
        int t = (threadIdx.x >= off) ? tmp[threadIdx.x - off] : 0;
        __syncthreads();
        tmp[threadIdx.x] += t;
        __syncthreads();
    }
    if (i < n) pos[i] = tmp[threadIdx.x] - v;      // exclusive
    if (threadIdx.x == 255) bsum[blockIdx.x] = tmp[255];
}

__global__ void k_scan_bsum(int* __restrict__ bsum, int nb) {
    __shared__ int tmp[256];
    int v = (threadIdx.x < nb) ? bsum[threadIdx.x] : 0;
    tmp[threadIdx.x] = v; __syncthreads();
    #pragma unroll
    for (int off = 1; off < 256; off <<= 1) {
        int t = (threadIdx.x >= off) ? tmp[threadIdx.x - off] : 0;
        __syncthreads();
        tmp[threadIdx.x] += t;
        __syncthreads();
    }
    if (threadIdx.x < nb) bsum[threadIdx.x] = tmp[threadIdx.x] - v;
}

__global__ void k_scan_add(int* __restrict__ pos, int n, const int* __restrict__ bsum) {
    int i = blockIdx.x * 256 + threadIdx.x;
    if (i < n) pos[i] += bsum[blockIdx.x];
}

// scatter using atomicSub on cnt (fills each bucket in reverse; order irrelevant)
__global__ void k_scatter(const int* __restrict__ ei, int E,
                          const int* __restrict__ rs, int* __restrict__ cnt,
                          int* __restrict__ col) {
    int e = blockIdx.x * 256 + threadIdx.x;
    if (e >= E) return;
    int s = ei[e], t = ei[E + e];
    int p = rs[t] + atomicSub(cnt + t, 1) - 1;
    col[p] = s;
}

// ---------------- fp32 -> bf16 cast of x ----------------

__global__ void k_cast(const float2* __restrict__ in, uint* __restrict__ out, int n2) {
    int i = blockIdx.x * 256 + threadIdx.x;
    if (i < n2) { float2 v = in[i]; out[i] = pack_bf16(v.x, v.y); }
}

// =========================================================================
// Layer-1 aggregation: one wave per dst node, bf16 rows (256 B), lane owns
// one dword (2 bf16). Unroll-by-4 edge loop -> 4 gathers in flight.
// Output bf16 for the fused GEMM.
// =========================================================================

__global__ __launch_bounds__(256) void k_agg_csr128(
    const int* __restrict__ rs, const int* __restrict__ col,
    const float* __restrict__ dinv, const uint* __restrict__ xb,
    uint* __restrict__ outb, int n, int E)
{
    int node = (blockIdx.x * 256 + threadIdx.x) >> 6;
    int lane = threadIdx.x & 63;
    if (node >= n) return;
    float di = dinv[node];
    int beg = rs[node];
    int end = (node + 1 < n) ? rs[node + 1] : E;
    uint u = xb[(size_t)node * 64 + lane];         // self loop
    float s = di * di;
    float ax = blo(u) * s, ay = bhi(u) * s;
    int j = beg;
    for (; j + 4 <= end; j += 4) {
        int s0 = col[j], s1 = col[j + 1], s2 = col[j + 2], s3 = col[j + 3];
        float n0 = dinv[s0] * di, n1 = dinv[s1] * di;
        float n2 = dinv[s2] * di, n3 = dinv[s3] * di;
        uint u0 = xb[(size_t)s0 * 64 + lane];
        uint u1 = xb[(size_t)s1 * 64 + lane];
        uint u2 = xb[(size_t)s2 * 64 + lane];
        uint u3 = xb[(size_t)s3 * 64 + lane];
        ax += blo(u0) * n0 + blo(u1) * n1 + blo(u2) * n2 + blo(u3) * n3;
        ay += bhi(u0) * n0 + bhi(u1) * n1 + bhi(u2) * n2 + bhi(u3) * n3;
    }
    for (; j < end; ++j) {
        int src = col[j];
        float nrm = dinv[src] * di;
        uint uu = xb[(size_t)src * 64 + lane];
        ax += blo(uu) * nrm; ay += bhi(uu) * nrm;
    }
    outb[(size_t)node * 64 + lane] = pack_bf16(ax, ay);
}

// =========================================================================
// Fused GEMM: h2[M,16] = relu(Ab[M,128] @ W1[128,256] + b1) @ W2[256,16]
// 64-row blocks, 4 n-tile passes; h never touches global memory.
// =========================================================================

__global__ __launch_bounds__(256) void k_gemm_fused(
    const uint* __restrict__ Ab,            // bf16 [M,128] viewed as dwords
    const float* __restrict__ W1, const float* __restrict__ b1,
    const float* __restrict__ W2,           // [256,16]
    float* __restrict__ H2, int M)
{
    __shared__ float As[64][132];
    __shared__ float Bs[128][64];
    const int t  = threadIdx.x;
    const int mb = blockIdx.x * 64;
    const int tx = t & 15, ty = t >> 4;

    // A tile: 64 rows x 128 bf16 = 1024 uint4 loads, convert -> fp32 LDS
    #pragma unroll
    for (int it = 0; it < 4; ++it) {
        int idx = it * 256 + t;
        int r = idx >> 4, c = idx & 15;
        int gr = mb + r;
        uint4 v = make_uint4(0u, 0u, 0u, 0u);
        if (gr < M) v = ((const uint4*)Ab)[(size_t)gr * 16 + c];
        float4 f0 = make_float4(blo(v.x), bhi(v.x), blo(v.y), bhi(v.y));
        float4 f1 = make_float4(blo(v.z), bhi(v.z), blo(v.w), bhi(v.w));
        *(float4*)&As[r][c * 8]     = f0;
        *(float4*)&As[r][c * 8 + 4] = f1;
    }

    float partial[4][16];
    #pragma unroll
    for (int i = 0; i < 4; ++i)
        #pragma unroll
        for (int o = 0; o < 16; ++o) partial[i][o] = 0.f;

    for (int nt = 0; nt < 4; ++nt) {
        __syncthreads();                      // As ready / previous Bs consumed
        #pragma unroll
        for (int it = 0; it < 8; ++it) {      // Bs: W1[128][nt*64 .. +64)
            int idx = it * 256 + t;
            int r = idx >> 4, c4 = idx & 15;
            *(float4*)&Bs[r][c4 << 2] =
                *(const float4*)(W1 + (size_t)r * 256 + nt * 64 + (c4 << 2));
        }
        __syncthreads();

        float acc[4][4] = {};
        #pragma unroll 8
        for (int k = 0; k < 128; ++k) {
            float a0 = As[ty * 4 + 0][k];
            float a1 = As[ty * 4 + 1][k];
            float a2 = As[ty * 4 + 2][k];
            float a3 = As[ty * 4 + 3][k];
            float4 b = *(const float4*)&Bs[k][tx << 2];
            acc[0][0] += a0 * b.x; acc[0][1] += a0 * b.y; acc[0][2] += a0 * b.z; acc[0][3] += a0 * b.w;
            acc[1][0] += a1 * b.x; acc[1][1] += a1 * b.y; acc[1][2] += a1 * b.z; acc[1][3] += a1 * b.w;
            acc[2][0] += a2 * b.x; acc[2][1] += a2 * b.y; acc[2][2] += a2 * b.z; acc[2][3] += a2 * b.w;
            acc[3][0] += a3 * b.x; acc[3][1] += a3 * b.y; acc[3][2] += a3 * b.z; acc[3][3] += a3 * b.w;
        }

        // bias + relu, then contract this 64-col slab of h with W2 into partial
        float4 bv = *(const float4*)(b1 + nt * 64 + (tx << 2));
        float bvv[4] = { bv.x, bv.y, bv.z, bv.w };
        #pragma unroll
        for (int jj = 0; jj < 4; ++jj) {
            int krow = nt * 64 + (tx << 2) + jj;   // gemm2 k index
            const float4* w2p = (const float4*)(W2 + (size_t)krow * 16);
            float4 w0 = w2p[0], w1v = w2p[1], w2v = w2p[2], w3 = w2p[3];
            #pragma unroll
            for (int i = 0; i < 4; ++i) {
                float hv = fmaxf(acc[i][jj] + bvv[jj], 0.f);
                partial[i][0]  += hv * w0.x;  partial[i][1]  += hv * w0.y;
                partial[i][2]  += hv * w0.z;  partial[i][3]  += hv * w0.w;
                partial[i][4]  += hv * w1v.x; partial[i][5]  += hv * w1v.y;
                partial[i][6]  += hv * w1v.z; partial[i][7]  += hv * w1v.w;
                partial[i][8]  += hv * w2v.x; partial[i][9]  += hv * w2v.y;
                partial[i][10] += hv * w2v.z; partial[i][11] += hv * w2v.w;
                partial[i][12] += hv * w3.x;  partial[i][13] += hv * w3.y;
                partial[i][14] += hv * w3.z;  partial[i][15] += hv * w3.w;
            }
        }
    }

    // reduce partial across tx (16 lanes) and write h2
    #pragma unroll
    for (int i = 0; i < 4; ++i) {
        float outv = 0.f;
        #pragma unroll
        for (int o = 0; o < 16; ++o) {
            float v = partial[i][o];
            v += __shfl_xor(v, 1, 16);
            v += __shfl_xor(v, 2, 16);
            v += __shfl_xor(v, 4, 16);
            v += __shfl_xor(v, 8, 16);
            if (o == tx) outv = v;
        }
        int gr = mb + ty * 4 + i;
        if (gr < M) H2[(size_t)gr * 16 + tx] = outv;
    }
}

// =========================================================================
// Layer-2 aggregation (D=16) + b2 + log_softmax. 16 lanes/node, unroll 4.
// =========================================================================

__global__ __launch_bounds__(256) void k_agg_csr16_lsm(
    const int* __restrict__ rs, const int* __restrict__ col,
    const float* __restrict__ dinv, const float* __restrict__ h2,
    const float* __restrict__ b2, float* __restrict__ out, int n, int E)
{
    int node = (blockIdx.x * 256 + threadIdx.x) >> 4;
    int lane = threadIdx.x & 15;
    if (node >= n) return;
    float di = dinv[node];
    int beg = rs[node];
    int end = (node + 1 < n) ? rs[node + 1] : E;
    float acc = h2[(size_t)node * 16 + lane] * di * di;   // self loop
    int j = beg;
    for (; j + 4 <= end; j += 4) {
        int s0 = col[j], s1 = col[j + 1], s2 = col[j + 2], s3 = col[j + 3];
        float n0 = dinv[s0] * di, n1 = dinv[s1] * di;
        float n2 = dinv[s2] * di, n3 = dinv[s3] * di;
        float v0 = h2[(size_t)s0 * 16 + lane];
        float v1 = h2[(size_t)s1 * 16 + lane];
        float v2 = h2[(size_t)s2 * 16 + lane];
        float v3 = h2[(size_t)s3 * 16 + lane];
        acc += v0 * n0 + v1 * n1 + v2 * n2 + v3 * n3;
    }
    for (; j < end; ++j) {
        int src = col[j];
        acc += h2[(size_t)src * 16 + lane] * (dinv[src] * di);
    }
    acc += b2[lane];
    float m = acc;
    #pragma unroll
    for (int msk = 1; msk < 16; msk <<= 1) m = fmaxf(m, __shfl_xor(m, msk, 16));
    float ex = __expf(acc - m);
    float ssum = ex;
    #pragma unroll
    for (int msk = 1; msk < 16; msk <<= 1) ssum += __shfl_xor(ssum, msk, 16);
    out[(size_t)node * 16 + lane] = acc - m - __logf(ssum);
}

// =========================================================================
// launcher
// =========================================================================

extern "C" void kernel_launch(void* const* d_in, const int* in_sizes, int n_in,
                              void* d_out, int out_size, void* d_ws, size_t ws_size,
                              hipStream_t stream) {
    const float* x  = (const float*)d_in[0];   // [N,128]
    const int*   ei = (const int*)d_in[1];     // [2,E]
    const float* W1 = (const float*)d_in[2];   // [128,256]
    const float* b1 = (const float*)d_in[3];   // [256]
    const float* W2 = (const float*)d_in[4];   // [256,16]
    const float* b2 = (const float*)d_in[5];   // [16]
    float* out = (float*)d_out;                // [N,16]

    const int N = in_sizes[0] / 128;           // 50000
    const int E = in_sizes[1] / 2;             // 800000

    // workspace layout (4-byte words from base)
    float* ws    = (float*)d_ws;
    float* dinv  = ws;                         // [0, 51200)
    int*   cnt   = (int*)(ws + 51200);         // counts, consumed by scatter
    int*   rs    = (int*)(ws + 102400);
    int*   bsum  = (int*)(ws + 153600);        // 1024
    int*   col   = (int*)(ws + 154624);        // E
    uint*  xb    = (uint*)(ws + 954624);       // bf16 x, N*64 dwords
    uint*  aggb  = (uint*)(ws + 4154624);      // bf16 agg, N*64 dwords
    float* h2    = ws + 7354624;               // N*16 fp32
    // total ~32.6 MB

    const int NB = (N + 255) / 256;            // 196

    // ---- CSR build + cast ----
    hipMemsetAsync(cnt, 0, (size_t)N * sizeof(int), stream);
    k_deg_count <<<(E + 255) / 256, 256, 0, stream>>>(ei, E, cnt);
    k_scan_block<<<NB, 256, 0, stream>>>(cnt, N, rs, bsum, dinv);
    k_scan_bsum <<<1, 256, 0, stream>>>(bsum, NB);
    k_scan_add  <<<NB, 256, 0, stream>>>(rs, N, bsum);
    k_scatter   <<<(E + 255) / 256, 256, 0, stream>>>(ei, E, rs, cnt, col);
    k_cast      <<<(N * 64 + 255) / 256, 256, 0, stream>>>((const float2*)x, xb, N * 64);

    // ---- layer 1 aggregate (bf16), fused GEMM1+relu+GEMM2 ----
    k_agg_csr128<<<(N * 64 + 255) / 256, 256, 0, stream>>>(rs, col, dinv, xb, aggb, N, E);
    k_gemm_fused<<<(N + 63) / 64, 256, 0, stream>>>(aggb, W1, b1, W2, h2, N);

    // ---- layer 2 aggregate + b2 + log_softmax ----
    k_agg_csr16_lsm<<<(N * 16 + 255) / 256, 256, 0, stream>>>(rs, col, dinv, h2, b2, out, N, E);
}

// Round 4
// 243.947 us; speedup vs baseline: 7.0859x; 1.2488x over previous
//
#include <hip/hip_runtime.h>
#include <math.h>

typedef unsigned int uint;
typedef short short8 __attribute__((ext_vector_type(8)));
typedef float floatx4 __attribute__((ext_vector_type(4)));

union U4S8 { uint4 u; short8 s; };

// ---------------- bf16 helpers (RNE round) ----------------

__device__ __forceinline__ float blo(uint u) { return __uint_as_float(u << 16); }
__device__ __forceinline__ float bhi(uint u) { return __uint_as_float(u & 0xffff0000u); }
__device__ __forceinline__ uint pack_bf16(float a, float b) {
    uint ua = __float_as_uint(a), ub = __float_as_uint(b);
    ua = (ua + 0x7fffu + ((ua >> 16) & 1u)) >> 16;
    ub = (ub + 0x7fffu + ((ub >> 16) & 1u)) >> 16;
    return ua | (ub << 16);
}
__device__ __forceinline__ unsigned short rb16(float f) {
    uint u = __float_as_uint(f);
    return (unsigned short)((u + 0x7fffu + ((u >> 16) & 1u)) >> 16);
}

// =========================================================================
// CSR build
// =========================================================================

__global__ void k_deg_count(const int* __restrict__ ei, int E, int* __restrict__ cnt) {
    int e = blockIdx.x * 256 + threadIdx.x;
    if (e < E) atomicAdd(cnt + ei[E + e], 1);      // dst row
}

__global__ void k_scan_block(const int* __restrict__ cnt, int n,
                             int* __restrict__ pos, int* __restrict__ bsum,
                             float* __restrict__ dinv) {
    __shared__ int tmp[256];
    int i = blockIdx.x * 256 + threadIdx.x;
    int v = (i < n) ? cnt[i] : 0;
    if (i < n) dinv[i] = rsqrtf((float)v + 1.0f);   // +1 self loop
    tmp[threadIdx.x] = v; __syncthreads();
    #pragma unroll
    for (int off = 1; off < 256; off <<= 1) {
        int t = (threadIdx.x >= off) ? tmp[threadIdx.x - off] : 0;
        __syncthreads();
        tmp[threadIdx.x] += t;
        __syncthreads();
    }
    if (i < n) pos[i] = tmp[threadIdx.x] - v;      // exclusive
    if (threadIdx.x == 255) bsum[blockIdx.x] = tmp[255];
}

__global__ void k_scan_bsum(int* __restrict__ bsum, int nb) {
    __shared__ int tmp[256];
    int v = (threadIdx.x < nb) ? bsum[threadIdx.x] : 0;
    tmp[threadIdx.x] = v; __syncthreads();
    #pragma unroll
    for (int off = 1; off < 256; off <<= 1) {
        int t = (threadIdx.x >= off) ? tmp[threadIdx.x - off] : 0;
        __syncthreads();
        tmp[threadIdx.x] += t;
        __syncthreads();
    }
    if (threadIdx.x < nb) bsum[threadIdx.x] = tmp[threadIdx.x] - v;
}

__global__ void k_scan_add(int* __restrict__ pos, int n, const int* __restrict__ bsum) {
    int i = blockIdx.x * 256 + threadIdx.x;
    if (i < n) pos[i] += bsum[blockIdx.x];
}

__global__ void k_scatter(const int* __restrict__ ei, int E,
                          const int* __restrict__ rs, int* __restrict__ cnt,
                          int* __restrict__ col) {
    int e = blockIdx.x * 256 + threadIdx.x;
    if (e >= E) return;
    int s = ei[e], t = ei[E + e];
    int p = rs[t] + atomicSub(cnt + t, 1) - 1;
    col[p] = s;
}

// ---------------- casts ----------------

__global__ void k_cast(const float2* __restrict__ in, uint* __restrict__ out, int n2) {
    int i = blockIdx.x * 256 + threadIdx.x;
    if (i < n2) { float2 v = in[i]; out[i] = pack_bf16(v.x, v.y); }
}

// W1 [128][256] -> W1t bf16 [256][128]; W2 [256][16] -> W2t bf16 [16][256]
__global__ void k_cast_w(const float* __restrict__ W1, const float* __restrict__ W2,
                         uint* __restrict__ W1t, uint* __restrict__ W2t) {
    int i = blockIdx.x * 256 + threadIdx.x;
    if (i < 16384) {
        int n = i >> 6, kd = i & 63;
        W1t[i] = pack_bf16(W1[(size_t)(2 * kd) * 256 + n], W1[(size_t)(2 * kd + 1) * 256 + n]);
    } else if (i < 16384 + 2048) {
        int j = i - 16384;
        int o = j >> 7, kd = j & 127;
        W2t[j] = pack_bf16(W2[(size_t)(2 * kd) * 16 + o], W2[(size_t)(2 * kd + 1) * 16 + o]);
    }
}

// =========================================================================
// Layer-1 aggregation (unchanged): one wave per node, bf16 rows.
// =========================================================================

__global__ __launch_bounds__(256) void k_agg_csr128(
    const int* __restrict__ rs, const int* __restrict__ col,
    const float* __restrict__ dinv, const uint* __restrict__ xb,
    uint* __restrict__ outb, int n, int E)
{
    int node = (blockIdx.x * 256 + threadIdx.x) >> 6;
    int lane = threadIdx.x & 63;
    if (node >= n) return;
    float di = dinv[node];
    int beg = rs[node];
    int end = (node + 1 < n) ? rs[node + 1] : E;
    uint u = xb[(size_t)node * 64 + lane];         // self loop
    float s = di * di;
    float ax = blo(u) * s, ay = bhi(u) * s;
    int j = beg;
    for (; j + 4 <= end; j += 4) {
        int s0 = col[j], s1 = col[j + 1], s2 = col[j + 2], s3 = col[j + 3];
        float n0 = dinv[s0] * di, n1 = dinv[s1] * di;
        float n2 = dinv[s2] * di, n3 = dinv[s3] * di;
        uint u0 = xb[(size_t)s0 * 64 + lane];
        uint u1 = xb[(size_t)s1 * 64 + lane];
        uint u2 = xb[(size_t)s2 * 64 + lane];
        uint u3 = xb[(size_t)s3 * 64 + lane];
        ax += blo(u0) * n0 + blo(u1) * n1 + blo(u2) * n2 + blo(u3) * n3;
        ay += bhi(u0) * n0 + bhi(u1) * n1 + bhi(u2) * n2 + bhi(u3) * n3;
    }
    for (; j < end; ++j) {
        int src = col[j];
        float nrm = dinv[src] * di;
        uint uu = xb[(size_t)src * 64 + lane];
        ax += blo(uu) * nrm; ay += bhi(uu) * nrm;
    }
    outb[(size_t)node * 64 + lane] = pack_bf16(ax, ay);
}

// =========================================================================
// Fused MFMA GEMM: h2[M,16] = relu(Ab[M,128]@W1 + b1) @ W2
// Block = 64 rows, 256 thr (4 waves). GEMM1: wave w owns cols [w*64,w*64+64),
// all 64 rows: 4 mtiles x 4 ntiles x 4 ksteps = 64 MFMAs, B-frags from global
// W1t (L2-resident). h (bf16) round-trips LDS (C-layout -> A-layout), then
// GEMM2: wave w owns rows [w*16,w*16+16): 8 MFMAs vs W2t.
// =========================================================================

__global__ __launch_bounds__(256) void k_gemm_mfma(
    const uint* __restrict__ Ab,       // bf16 [M,128] (64 dwords/row)
    const uint* __restrict__ W1t,      // bf16 [256][128] (64 dwords/row)
    const float* __restrict__ b1,
    const uint* __restrict__ W2t,      // bf16 [16][256] (128 dwords/row)
    float* __restrict__ H2, int M)
{
    __shared__ uint Alds[64 * 68];     // 64 rows x (64 + 4 pad) dwords = 17 KB
    __shared__ uint Hlds[64 * 132];    // 64 rows x (128 + 4 pad) dwords = 33 KB

    const int t    = threadIdx.x;
    const int mb   = blockIdx.x * 64;
    const int wv   = t >> 6;
    const int lane = t & 63;
    const int c    = lane & 15;        // 16-lane sub-index
    const int q    = lane >> 4;        // quad

    // ---- stage A tile: 64 rows x 64 dwords ----
    #pragma unroll
    for (int it = 0; it < 4; ++it) {
        int i = it * 256 + t;          // 1024 uint4s
        int r = i >> 4, cc = i & 15;
        int gr = mb + r;
        uint4 v = make_uint4(0u, 0u, 0u, 0u);
        if (gr < M) v = ((const uint4*)Ab)[(size_t)gr * 16 + cc];
        *(uint4*)&Alds[r * 68 + cc * 4] = v;
    }
    __syncthreads();

    // ---- GEMM1: 64 MFMAs ----
    floatx4 acc[4][4];                 // [mtile][ntile]
    #pragma unroll
    for (int i = 0; i < 4; ++i)
        #pragma unroll
        for (int jj = 0; jj < 4; ++jj) acc[i][jj] = (floatx4)0.f;

    #pragma unroll
    for (int kk = 0; kk < 4; ++kk) {
        U4S8 af[4];
        #pragma unroll
        for (int mt = 0; mt < 4; ++mt)
            af[mt].u = *(const uint4*)&Alds[(mt * 16 + c) * 68 + kk * 16 + q * 4];
        #pragma unroll
        for (int nt = 0; nt < 4; ++nt) {
            int n = wv * 64 + nt * 16 + c;
            U4S8 bf;
            bf.u = ((const uint4*)W1t)[(size_t)n * 16 + kk * 4 + q];
            #pragma unroll
            for (int mt = 0; mt < 4; ++mt)
                acc[mt][nt] = __builtin_amdgcn_mfma_f32_16x16x32_bf16(
                    af[mt].s, bf.s, acc[mt][nt], 0, 0, 0);
        }
    }

    // ---- epilogue 1: bias + relu, pack bf16 into Hlds ----
    float b1v[4];
    #pragma unroll
    for (int nt = 0; nt < 4; ++nt) b1v[nt] = b1[wv * 64 + nt * 16 + c];

    unsigned short* hs = (unsigned short*)Hlds;     // row stride 264 shorts
    #pragma unroll
    for (int mt = 0; mt < 4; ++mt)
        #pragma unroll
        for (int nt = 0; nt < 4; ++nt)
            #pragma unroll
            for (int r = 0; r < 4; ++r) {
                float hv = fmaxf(acc[mt][nt][r] + b1v[nt], 0.f);
                int row = mt * 16 + q * 4 + r;
                int colc = wv * 64 + nt * 16 + c;
                hs[row * 264 + colc] = rb16(hv);
            }
    __syncthreads();

    // ---- GEMM2: wave w -> rows [w*16, w*16+16), 8 MFMAs vs W2t ----
    floatx4 acc2 = (floatx4)0.f;
    #pragma unroll
    for (int kk = 0; kk < 8; ++kk) {
        U4S8 av, bv;
        av.u = *(const uint4*)&Hlds[(wv * 16 + c) * 132 + kk * 16 + q * 4];
        bv.u = ((const uint4*)W2t)[(size_t)c * 32 + kk * 4 + q];
        acc2 = __builtin_amdgcn_mfma_f32_16x16x32_bf16(av.s, bv.s, acc2, 0, 0, 0);
    }
    #pragma unroll
    for (int r = 0; r < 4; ++r) {
        int gr = mb + wv * 16 + q * 4 + r;
        if (gr < M) H2[(size_t)gr * 16 + c] = acc2[r];
    }
}

// =========================================================================
// Layer-2 aggregation (D=16) + b2 + log_softmax
// =========================================================================

__global__ __launch_bounds__(256) void k_agg_csr16_lsm(
    const int* __restrict__ rs, const int* __restrict__ col,
    const float* __restrict__ dinv, const float* __restrict__ h2,
    const float* __restrict__ b2, float* __restrict__ out, int n, int E)
{
    int node = (blockIdx.x * 256 + threadIdx.x) >> 4;
    int lane = threadIdx.x & 15;
    if (node >= n) return;
    float di = dinv[node];
    int beg = rs[node];
    int end = (node + 1 < n) ? rs[node + 1] : E;
    float acc = h2[(size_t)node * 16 + lane] * di * di;   // self loop
    int j = beg;
    for (; j + 4 <= end; j += 4) {
        int s0 = col[j], s1 = col[j + 1], s2 = col[j + 2], s3 = col[j + 3];
        float n0 = dinv[s0] * di, n1 = dinv[s1] * di;
        float n2 = dinv[s2] * di, n3 = dinv[s3] * di;
        float v0 = h2[(size_t)s0 * 16 + lane];
        float v1 = h2[(size_t)s1 * 16 + lane];
        float v2 = h2[(size_t)s2 * 16 + lane];
        float v3 = h2[(size_t)s3 * 16 + lane];
        acc += v0 * n0 + v1 * n1 + v2 * n2 + v3 * n3;
    }
    for (; j < end; ++j) {
        int src = col[j];
        acc += h2[(size_t)src * 16 + lane] * (dinv[src] * di);
    }
    acc += b2[lane];
    float m = acc;
    #pragma unroll
    for (int msk = 1; msk < 16; msk <<= 1) m = fmaxf(m, __shfl_xor(m, msk, 16));
    float ex = __expf(acc - m);
    float ssum = ex;
    #pragma unroll
    for (int msk = 1; msk < 16; msk <<= 1) ssum += __shfl_xor(ssum, msk, 16);
    out[(size_t)node * 16 + lane] = acc - m - __logf(ssum);
}

// =========================================================================
// launcher
// =========================================================================

extern "C" void kernel_launch(void* const* d_in, const int* in_sizes, int n_in,
                              void* d_out, int out_size, void* d_ws, size_t ws_size,
                              hipStream_t stream) {
    const float* x  = (const float*)d_in[0];   // [N,128]
    const int*   ei = (const int*)d_in[1];     // [2,E]
    const float* W1 = (const float*)d_in[2];   // [128,256]
    const float* b1 = (const float*)d_in[3];   // [256]
    const float* W2 = (const float*)d_in[4];   // [256,16]
    const float* b2 = (const float*)d_in[5];   // [16]
    float* out = (float*)d_out;                // [N,16]

    const int N = in_sizes[0] / 128;           // 50000
    const int E = in_sizes[1] / 2;             // 800000

    // workspace (4-byte words from base)
    float* ws    = (float*)d_ws;
    float* dinv  = ws;                         // 51200
    int*   cnt   = (int*)(ws + 51200);
    int*   rs    = (int*)(ws + 102400);
    int*   bsum  = (int*)(ws + 153600);        // 1024
    int*   col   = (int*)(ws + 154624);        // E
    uint*  xb    = (uint*)(ws + 954624);       // N*64
    uint*  aggb  = (uint*)(ws + 4154624);      // N*64
    float* h2    = ws + 7354624;               // N*16
    uint*  W1t   = (uint*)(ws + 8154624);      // 16384
    uint*  W2t   = (uint*)(ws + 8171008);      // 2048
    // total ~32.7 MB

    const int NB = (N + 255) / 256;            // 196

    // ---- CSR build + casts ----
    hipMemsetAsync(cnt, 0, (size_t)N * sizeof(int), stream);
    k_deg_count <<<(E + 255) / 256, 256, 0, stream>>>(ei, E, cnt);
    k_scan_block<<<NB, 256, 0, stream>>>(cnt, N, rs, bsum, dinv);
    k_scan_bsum <<<1, 256, 0, stream>>>(bsum, NB);
    k_scan_add  <<<NB, 256, 0, stream>>>(rs, N, bsum);
    k_scatter   <<<(E + 255) / 256, 256, 0, stream>>>(ei, E, rs, cnt, col);
    k_cast      <<<(N * 64 + 255) / 256, 256, 0, stream>>>((const float2*)x, xb, N * 64);
    k_cast_w    <<<72, 256, 0, stream>>>(W1, W2, W1t, W2t);

    // ---- layer 1 aggregate, fused MFMA GEMM1+relu+GEMM2 ----
    k_agg_csr128<<<(N * 64 + 255) / 256, 256, 0, stream>>>(rs, col, dinv, xb, aggb, N, E);
    k_gemm_mfma <<<(N + 63) / 64, 256, 0, stream>>>(aggb, W1t, b1, W2t, h2, N);

    // ---- layer 2 aggregate + b2 + log_softmax ----
    k_agg_csr16_lsm<<<(N * 16 + 255) / 256, 256, 0, stream>>>(rs, col, dinv, h2, b2, out, N, E);
}